// Round 2
// baseline (151.839 us; speedup 1.0000x reference)
//
#include <hip/hip_runtime.h>
#include <math.h>

// ActELoss, symmetric reformulation, single-dispatch atomic-ticket reduction.
// S = sum_{b,i,j=0..10} exp(-|a0[i]-p0[i+j]|/2)*|a2[i]-p2[i+j]|, p = pad(6 first,5 last)
// Symmetry f(i,m)=f(m,i), f(i,i)=0:
//   S = 2*sum_{k=1..4} sum_i f(i,i+k) + sum_{k=5,6} sum_i f(i,i+k)
//     + sum_{i=1..5}(6-i) f(i,0) + sum_{i=746..748}(i-745) f(i,749)
// plus 0.1 * sum_b ||a0-a2||_2.
//
// R5 NOTE (R4 lesson): cooperative launch + grid.sync wedged the container —
// grid-sync is NOT harness-safe under graph capture. This version fuses the
// final reduction via the rocPRIM-style atomic-ticket "last block" pattern:
// deadlock-free by construction (no spin, no co-residency requirement).
// Ticket counter lives in ws, zeroed by a capture-safe 4-byte hipMemsetAsync.
// Final summation replicates the old actloss_final order bitwise.

#define T_LEN 750
#define BLK   256
#define CPT   3            // positions per thread; 250 active threads
#define NACT  (T_LEN / CPT)
#define SPAD  756          // staged length: need reads up to i0+8 = 755
#define L2E_HALF 0.72134752044f   // 0.5 * log2(e)

__global__ __launch_bounds__(BLK) void actloss_fused(
    const float* __restrict__ a0, const float* __restrict__ a2,
    float* __restrict__ partials, unsigned int* __restrict__ ticket,
    float* __restrict__ out, int nblk)
{
    __shared__ float s0[SPAD];
    __shared__ float s2[SPAD];

    const int b   = blockIdx.x;
    const int tid = threadIdx.x;
    const float* __restrict__ g0 = a0 + (size_t)b * T_LEN;
    const float* __restrict__ g2 = a2 + (size_t)b * T_LEN;

    // Stage rows as float2 (rows are 8B-aligned: b*750*4 % 8 == 0).
    {
        const float2* __restrict__ v0 = (const float2*)g0;
        const float2* __restrict__ v2 = (const float2*)g2;
        for (int k = tid; k < 375; k += BLK) {
            const float2 x0 = v0[k];
            const float2 x2 = v2[k];
            s0[2 * k]     = x0.x;
            s0[2 * k + 1] = x0.y;
            s2[2 * k]     = x2.x;
            s2[2 * k + 1] = x2.y;
        }
        // tail pad [750..755]: replicate last element (contributions masked)
        if (tid < SPAD - T_LEN) {
            s0[T_LEN + tid] = g0[T_LEN - 1];
            s2[T_LEN + tid] = g2[T_LEN - 1];
        }
    }
    __syncthreads();

    float loss1 = 0.0f;   // weight-1 terms (k=5,6 and edge extras)
    float loss2 = 0.0f;   // weight-2 terms (k=1..4)
    float sq    = 0.0f;

    if (tid < NACT) {
        const int i0 = tid * CPT;
        float r0[CPT + 6], r2[CPT + 6];
#pragma unroll
        for (int k = 0; k < CPT + 6; ++k) {
            r0[k] = s0[i0 + k];
            r2[k] = s2[i0 + k];
        }
#pragma unroll
        for (int ci = 0; ci < CPT; ++ci) {
            const float c0 = r0[ci];
            const float c2 = r2[ci];
#pragma unroll
            for (int k = 1; k <= 6; ++k) {
                const float wv  = __builtin_amdgcn_exp2f(
                                      -L2E_HALF * fabsf(c0 - r0[ci + k]));
                float ad2 = fabsf(c2 - r2[ci + k]);
                ad2 = (i0 + ci + k < T_LEN) ? ad2 : 0.0f;   // drop out-of-range pairs
                if (k <= 4) loss2 = fmaf(wv, ad2, loss2);
                else        loss1 = fmaf(wv, ad2, loss1);
            }
            const float d = c0 - c2;
            sq = fmaf(d, d, sq);
        }
    } else if (tid == NACT) {
        // clamp edge extras (8 terms)
#pragma unroll
        for (int i = 1; i <= 5; ++i) {
            const float wv = __builtin_amdgcn_exp2f(-L2E_HALF * fabsf(s0[i] - s0[0]));
            loss1 = fmaf(wv * (float)(6 - i), fabsf(s2[i] - s2[0]), loss1);
        }
#pragma unroll
        for (int i = 746; i <= 748; ++i) {
            const float wv = __builtin_amdgcn_exp2f(-L2E_HALF * fabsf(s0[i] - s0[T_LEN - 1]));
            loss1 = fmaf(wv * (float)(i - 745), fabsf(s2[i] - s2[T_LEN - 1]), loss1);
        }
    }

    float loss = fmaf(2.0f, loss2, loss1);

    // wave64 shuffle reduce
#pragma unroll
    for (int off = 32; off > 0; off >>= 1) {
        loss += __shfl_down(loss, off, 64);
        sq   += __shfl_down(sq,   off, 64);
    }
    __shared__ float rl[BLK / 64], rs[BLK / 64];
    const int wid  = tid >> 6;
    const int lane = tid & 63;
    if (lane == 0) { rl[wid] = loss; rs[wid] = sq; }
    __syncthreads();

    __shared__ int isLast;
    if (tid == 0) {
        float L = 0.0f, S = 0.0f;
#pragma unroll
        for (int w = 0; w < BLK / 64; ++w) { L += rl[w]; S += rs[w]; }
        partials[b] = L + 0.1f * sqrtf(S);
        // release: make the partial visible device-wide, then take a ticket
        __threadfence();
        const unsigned int t = atomicAdd(ticket, 1u);
        isLast = (t == (unsigned int)nblk - 1u) ? 1 : 0;
    }
    __syncthreads();

    if (isLast) {
        // acquire: all other blocks' partials are now visible
        __threadfence();
        // --- bitwise-identical to the old actloss_final ---
        const int n4 = nblk / 4;
        const float4* __restrict__ p4 = (const float4*)partials;
        float v = 0.0f;
        for (int k = tid; k < n4; k += BLK) {
            const float4 x = p4[k];
            v += (x.x + x.y) + (x.z + x.w);
        }
#pragma unroll
        for (int off = 32; off > 0; off >>= 1) v += __shfl_down(v, off, 64);
        if (lane == 0) rl[wid] = v;
        __syncthreads();
        if (tid == 0) {
            float s = 0.0f;
#pragma unroll
            for (int w = 0; w < BLK / 64; ++w) s += rl[w];
            out[0] = s;
        }
    }
}

extern "C" void kernel_launch(void* const* d_in, const int* in_sizes, int n_in,
                              void* d_out, int out_size, void* d_ws, size_t ws_size,
                              hipStream_t stream)
{
    const float* a0 = (const float*)d_in[0];
    const float* a2 = (const float*)d_in[1];
    float* out      = (float*)d_out;
    float* partials = (float*)d_ws;              // B floats, fully overwritten
    const int B = in_sizes[0] / T_LEN;           // 4096

    // ticket counter right after partials (offset 16 KiB, 4-aligned)
    unsigned int* ticket = (unsigned int*)((char*)d_ws + (size_t)B * sizeof(float));

    // capture-safe: memset is a supported graph node (harness reset uses them)
    hipMemsetAsync((void*)ticket, 0, sizeof(unsigned int), stream);

    actloss_fused<<<B, BLK, 0, stream>>>(a0, a2, partials, ticket, out, B);
}

// Round 3
// 91.629 us; speedup vs baseline: 1.6571x; 1.6571x over previous
//
#include <hip/hip_runtime.h>
#include <math.h>

// ActELoss, symmetric reformulation, single-dispatch, contention-free fused reduce.
// S = sum_{b,i,j=0..10} exp(-|a0[i]-p0[i+j]|/2)*|a2[i]-p2[i+j]|, p = pad(6 first,5 last)
// Symmetry f(i,m)=f(m,i), f(i,i)=0:
//   S = 2*sum_{k=1..4} sum_i f(i,i+k) + sum_{k=5,6} sum_i f(i,i+k)
//     + sum_{i=1..5}(6-i) f(i,0) + sum_{i=746..748}(i-745) f(i,749)
// plus 0.1 * sum_b ||a0-a2||_2.
//
// R6 post-mortem of R5: single ticket counter = 4096 same-address atomicAdds
// (+4096 threadfences) -> ~70 us serialized tail (kernel 90 us, all pipes idle).
// This was the original R3 lesson re-learned. Fix while KEEPING one dispatch:
//   - 1024 blocks x 4 rows (rows contiguous -> float4 staging, 24KB LDS, 6 blk/CU)
//   - hierarchical tickets: 32 spread counters (64B apart, parallel L2 channels)
//     + 1 master counter touched by only 32 blocks -> tail < 1 us
//   - partials remain PER-ROW with R0's exact thread mapping + reduce tree, and
//     the last block replays the old actloss_final verbatim -> bitwise-identical
//     output (absmax must stay 0.0).

#define T_LEN 750
#define BLK   256
#define CPT   3            // positions per thread; 250 active threads per row
#define NACT  (T_LEN / CPT)
#define RPB   4            // rows per block
#define NGRP  32           // spread ticket counters
#define L2E_HALF 0.72134752044f   // 0.5 * log2(e)

__global__ __launch_bounds__(BLK) void actloss_fused(
    const float* __restrict__ a0, const float* __restrict__ a2,
    float* __restrict__ partials, unsigned int* __restrict__ tickets,
    float* __restrict__ out, int nblk, int nrows)
{
    // Flat 4-row staging: rows r at s[r*750]; 8 pad floats at [3000..3007].
    // Out-of-row reads (i0+k >= 750) hit the next row's head / pad: any finite
    // value is fine because ad2 is masked to 0 for those terms.
    __shared__ float4 s0v[752];
    __shared__ float4 s2v[752];
    float* s0 = (float*)s0v;
    float* s2 = (float*)s2v;
    __shared__ float rl[RPB][BLK / 64], rs[RPB][BLK / 64];
    __shared__ float rf[BLK / 64];
    __shared__ int   isLast;

    const int b   = blockIdx.x;
    const int tid = threadIdx.x;
    const int b0  = b * RPB;

    // 4 contiguous rows = 3000 floats = 750 float4 (base byte offset b0*3000 % 16 == 0)
    const float* __restrict__ g0 = a0 + (size_t)b0 * T_LEN;
    const float* __restrict__ g2 = a2 + (size_t)b0 * T_LEN;
    {
        const float4* __restrict__ v0 = (const float4*)g0;
        const float4* __restrict__ v2 = (const float4*)g2;
        for (int k = tid; k < 750; k += BLK) {
            s0v[k] = v0[k];
            s2v[k] = v2[k];
        }
        if (tid < 8) {            // pad: replicate last element (masked anyway)
            s0[3000 + tid] = g0[RPB * T_LEN - 1];
            s2[3000 + tid] = g2[RPB * T_LEN - 1];
        }
    }
    __syncthreads();

    float lossA[RPB], sqA[RPB];
#pragma unroll
    for (int r = 0; r < RPB; ++r) { lossA[r] = 0.0f; sqA[r] = 0.0f; }

    if (tid < NACT) {
        const int i0 = tid * CPT;
#pragma unroll
        for (int r = 0; r < RPB; ++r) {
            const float* __restrict__ s0r = s0 + r * T_LEN;
            const float* __restrict__ s2r = s2 + r * T_LEN;
            float r0[CPT + 6], r2[CPT + 6];
#pragma unroll
            for (int k = 0; k < CPT + 6; ++k) {
                r0[k] = s0r[i0 + k];
                r2[k] = s2r[i0 + k];
            }
            float loss1 = 0.0f, loss2 = 0.0f, sq = 0.0f;
#pragma unroll
            for (int ci = 0; ci < CPT; ++ci) {
                const float c0 = r0[ci];
                const float c2 = r2[ci];
#pragma unroll
                for (int k = 1; k <= 6; ++k) {
                    const float wv  = __builtin_amdgcn_exp2f(
                                          -L2E_HALF * fabsf(c0 - r0[ci + k]));
                    float ad2 = fabsf(c2 - r2[ci + k]);
                    ad2 = (i0 + ci + k < T_LEN) ? ad2 : 0.0f;  // mask out-of-range
                    if (k <= 4) loss2 = fmaf(wv, ad2, loss2);
                    else        loss1 = fmaf(wv, ad2, loss1);
                }
                const float d = c0 - c2;
                sq = fmaf(d, d, sq);
            }
            lossA[r] = fmaf(2.0f, loss2, loss1);
            sqA[r]   = sq;
        }
    } else if (tid == NACT) {
        // clamp edge extras (8 terms per row)
#pragma unroll
        for (int r = 0; r < RPB; ++r) {
            const float* __restrict__ s0r = s0 + r * T_LEN;
            const float* __restrict__ s2r = s2 + r * T_LEN;
            float loss1 = 0.0f;
#pragma unroll
            for (int i = 1; i <= 5; ++i) {
                const float wv = __builtin_amdgcn_exp2f(-L2E_HALF * fabsf(s0r[i] - s0r[0]));
                loss1 = fmaf(wv * (float)(6 - i), fabsf(s2r[i] - s2r[0]), loss1);
            }
#pragma unroll
            for (int i = 746; i <= 748; ++i) {
                const float wv = __builtin_amdgcn_exp2f(-L2E_HALF * fabsf(s0r[i] - s0r[T_LEN - 1]));
                loss1 = fmaf(wv * (float)(i - 745), fabsf(s2r[i] - s2r[T_LEN - 1]), loss1);
            }
            lossA[r] = fmaf(2.0f, 0.0f, loss1);   // match R0's edge-thread value
        }
    }

    // wave64 shuffle reduce, all 4 rows in one pass (tree identical to R0 per row)
#pragma unroll
    for (int off = 32; off > 0; off >>= 1) {
#pragma unroll
        for (int r = 0; r < RPB; ++r) {
            lossA[r] += __shfl_down(lossA[r], off, 64);
            sqA[r]   += __shfl_down(sqA[r],   off, 64);
        }
    }
    const int wid  = tid >> 6;
    const int lane = tid & 63;
    if (lane == 0) {
#pragma unroll
        for (int r = 0; r < RPB; ++r) { rl[r][wid] = lossA[r]; rs[r][wid] = sqA[r]; }
    }
    __syncthreads();

    if (tid == 0) {
        float4 p;
        float* pp = (float*)&p;
#pragma unroll
        for (int r = 0; r < RPB; ++r) {
            float L = 0.0f, S = 0.0f;
#pragma unroll
            for (int w = 0; w < BLK / 64; ++w) { L += rl[r][w]; S += rs[r][w]; }
            pp[r] = L + 0.1f * sqrtf(S);          // same per-row value as R0
        }
        *(float4*)&partials[b0] = p;              // b0*4B is 16B-aligned
        // release partials, then take a spread ticket (32 counters, 64B apart)
        __threadfence();
        const unsigned int t = atomicAdd(&tickets[(b & (NGRP - 1)) * 16], 1u);
        int last = 0;
        if (t == (unsigned int)(nblk / NGRP) - 1u) {     // last in group
            __threadfence();
            const unsigned int m = atomicAdd(&tickets[NGRP * 16], 1u);
            last = (m == NGRP - 1u);                     // last group overall
        }
        isLast = last;
    }
    __syncthreads();

    if (isLast) {
        __threadfence();   // acquire: all partials visible
        // --- bitwise-identical to the old actloss_final ---
        const int n4 = nrows / 4;
        const float4* __restrict__ p4 = (const float4*)partials;
        float v = 0.0f;
        for (int k = tid; k < n4; k += BLK) {
            const float4 x = p4[k];
            v += (x.x + x.y) + (x.z + x.w);
        }
#pragma unroll
        for (int off = 32; off > 0; off >>= 1) v += __shfl_down(v, off, 64);
        if (lane == 0) rf[wid] = v;
        __syncthreads();
        if (tid == 0) {
            float s = 0.0f;
#pragma unroll
            for (int w = 0; w < BLK / 64; ++w) s += rf[w];
            out[0] = s;
        }
    }
}

extern "C" void kernel_launch(void* const* d_in, const int* in_sizes, int n_in,
                              void* d_out, int out_size, void* d_ws, size_t ws_size,
                              hipStream_t stream)
{
    const float* a0 = (const float*)d_in[0];
    const float* a2 = (const float*)d_in[1];
    float* out      = (float*)d_out;
    float* partials = (float*)d_ws;              // B floats, fully overwritten
    const int B = in_sizes[0] / T_LEN;           // 4096

    // tickets right after partials: 32 counters at 64B stride + 1 master
    unsigned int* tickets = (unsigned int*)((char*)d_ws + (size_t)B * sizeof(float));

    // capture-safe zeroing (memset nodes are supported; proven in R5)
    hipMemsetAsync((void*)tickets, 0, (NGRP * 16 + 16) * sizeof(unsigned int), stream);

    const int nblk = B / RPB;                    // 1024, divisible by NGRP=32
    actloss_fused<<<nblk, BLK, 0, stream>>>(a0, a2, partials, tickets, out, nblk, B);
}

// Round 4
// 76.560 us; speedup vs baseline: 1.9833x; 1.1968x over previous
//
#include <hip/hip_runtime.h>
#include <math.h>

// ActELoss, symmetric reformulation, two-kernel (the structure that wins).
// S = sum_{b,i,j=0..10} exp(-|a0[i]-p0[i+j]|/2)*|a2[i]-p2[i+j]|, p = pad(6 first,5 last)
// Symmetry f(i,m)=f(m,i), f(i,i)=0:
//   S = 2*sum_{k=1..4} sum_i f(i,i+k) + sum_{k=5,6} sum_i f(i,i+k)
//     + sum_{i=1..5}(6-i) f(i,0) + sum_{i=746..748}(i-745) f(i,749)
// plus 0.1 * sum_b ||a0-a2||_2.
//
// SESSION LESSONS (do not re-learn):
//  R1: cooperative launch / grid.sync wedges the container under graph capture.
//  R2: single-address atomicAdd ticket: 4096 x ~17ns serialized = ~70us tail.
//  R3: spread tickets fixed atomics, but __threadfence() (device release) lowers
//      to buffer_wbl2 L2-writeback on gfx950's 8 non-coherent L2s: 1024 fences
//      ~= 15us. ANY in-kernel device-scope release loses to the ~5us dispatch
//      boundary, whose cache flush/invalidate is hardware-enforced and free.
// => Two dispatches, zero atomics/fences. Improvements kept from R3 (proven
//    absmax 0.0): 4-row blocks, float4 flat LDS staging, resident 1024-block
//    grid. New: block pre-sums its 4 row-partials in the old final kernel's
//    exact quad order -> final reads 4KB/1 iter instead of 16KB/4 iters.

#define T_LEN 750
#define BLK   256
#define CPT   3            // positions per thread; 250 active threads per row
#define NACT  (T_LEN / CPT)
#define RPB   4            // rows per block
#define L2E_HALF 0.72134752044f   // 0.5 * log2(e)

__global__ __launch_bounds__(BLK) void actloss_partial(
    const float* __restrict__ a0, const float* __restrict__ a2,
    float* __restrict__ partials)
{
    // Flat 4-row staging: rows r at s[r*750]; 8 pad floats at [3000..3007].
    // Out-of-row reads (i0+k >= 750) hit the next row's head / pad: any finite
    // value is fine because ad2 is masked to 0 for those terms.
    __shared__ float4 s0v[752];
    __shared__ float4 s2v[752];
    float* s0 = (float*)s0v;
    float* s2 = (float*)s2v;
    __shared__ float rl[RPB][BLK / 64], rs[RPB][BLK / 64];

    const int b   = blockIdx.x;
    const int tid = threadIdx.x;
    const int b0  = b * RPB;

    // 4 contiguous rows = 3000 floats = 750 float4 (base byte offset b0*3000*4 % 16 == 0)
    const float* __restrict__ g0 = a0 + (size_t)b0 * T_LEN;
    const float* __restrict__ g2 = a2 + (size_t)b0 * T_LEN;
    {
        const float4* __restrict__ v0 = (const float4*)g0;
        const float4* __restrict__ v2 = (const float4*)g2;
        for (int k = tid; k < 750; k += BLK) {
            s0v[k] = v0[k];
            s2v[k] = v2[k];
        }
        if (tid < 8) {            // pad: replicate last element (masked anyway)
            s0[3000 + tid] = g0[RPB * T_LEN - 1];
            s2[3000 + tid] = g2[RPB * T_LEN - 1];
        }
    }
    __syncthreads();

    float lossA[RPB], sqA[RPB];
#pragma unroll
    for (int r = 0; r < RPB; ++r) { lossA[r] = 0.0f; sqA[r] = 0.0f; }

    if (tid < NACT) {
        const int i0 = tid * CPT;
#pragma unroll
        for (int r = 0; r < RPB; ++r) {
            const float* __restrict__ s0r = s0 + r * T_LEN;
            const float* __restrict__ s2r = s2 + r * T_LEN;
            float r0[CPT + 6], r2[CPT + 6];
#pragma unroll
            for (int k = 0; k < CPT + 6; ++k) {
                r0[k] = s0r[i0 + k];
                r2[k] = s2r[i0 + k];
            }
            float loss1 = 0.0f, loss2 = 0.0f, sq = 0.0f;
#pragma unroll
            for (int ci = 0; ci < CPT; ++ci) {
                const float c0 = r0[ci];
                const float c2 = r2[ci];
#pragma unroll
                for (int k = 1; k <= 6; ++k) {
                    const float wv  = __builtin_amdgcn_exp2f(
                                          -L2E_HALF * fabsf(c0 - r0[ci + k]));
                    float ad2 = fabsf(c2 - r2[ci + k]);
                    ad2 = (i0 + ci + k < T_LEN) ? ad2 : 0.0f;  // mask out-of-range
                    if (k <= 4) loss2 = fmaf(wv, ad2, loss2);
                    else        loss1 = fmaf(wv, ad2, loss1);
                }
                const float d = c0 - c2;
                sq = fmaf(d, d, sq);
            }
            lossA[r] = fmaf(2.0f, loss2, loss1);
            sqA[r]   = sq;
        }
    } else if (tid == NACT) {
        // clamp edge extras (8 terms per row)
#pragma unroll
        for (int r = 0; r < RPB; ++r) {
            const float* __restrict__ s0r = s0 + r * T_LEN;
            const float* __restrict__ s2r = s2 + r * T_LEN;
            float loss1 = 0.0f;
#pragma unroll
            for (int i = 1; i <= 5; ++i) {
                const float wv = __builtin_amdgcn_exp2f(-L2E_HALF * fabsf(s0r[i] - s0r[0]));
                loss1 = fmaf(wv * (float)(6 - i), fabsf(s2r[i] - s2r[0]), loss1);
            }
#pragma unroll
            for (int i = 746; i <= 748; ++i) {
                const float wv = __builtin_amdgcn_exp2f(-L2E_HALF * fabsf(s0r[i] - s0r[T_LEN - 1]));
                loss1 = fmaf(wv * (float)(i - 745), fabsf(s2r[i] - s2r[T_LEN - 1]), loss1);
            }
            lossA[r] = loss1;
        }
    }

    // wave64 shuffle reduce, all 4 rows in one pass (tree identical to R0 per row)
#pragma unroll
    for (int off = 32; off > 0; off >>= 1) {
#pragma unroll
        for (int r = 0; r < RPB; ++r) {
            lossA[r] += __shfl_down(lossA[r], off, 64);
            sqA[r]   += __shfl_down(sqA[r],   off, 64);
        }
    }
    const int wid  = tid >> 6;
    const int lane = tid & 63;
    if (lane == 0) {
#pragma unroll
        for (int r = 0; r < RPB; ++r) { rl[r][wid] = lossA[r]; rs[r][wid] = sqA[r]; }
    }
    __syncthreads();

    if (tid == 0) {
        float p[RPB];
#pragma unroll
        for (int r = 0; r < RPB; ++r) {
            float L = 0.0f, S = 0.0f;
#pragma unroll
            for (int w = 0; w < BLK / 64; ++w) { L += rl[r][w]; S += rs[r][w]; }
            p[r] = L + 0.1f * sqrtf(S);          // same per-row value as R0
        }
        // pre-sum in the old final kernel's exact quad order: (x+y)+(z+w)
        partials[b] = (p[0] + p[1]) + (p[2] + p[3]);
    }
}

__global__ __launch_bounds__(BLK) void actloss_final(
    const float* __restrict__ partials, int n4, float* __restrict__ out)
{
    // n4 = number of float4s (1024 partials / 4 = 256): one per thread.
    const float4* __restrict__ p4 = (const float4*)partials;
    float v = 0.0f;
    for (int k = threadIdx.x; k < n4; k += BLK) {
        const float4 x = p4[k];
        v += (x.x + x.y) + (x.z + x.w);
    }
#pragma unroll
    for (int off = 32; off > 0; off >>= 1) v += __shfl_down(v, off, 64);
    __shared__ float r[BLK / 64];
    if ((threadIdx.x & 63) == 0) r[threadIdx.x >> 6] = v;
    __syncthreads();
    if (threadIdx.x == 0) {
        float s = 0.0f;
#pragma unroll
        for (int w = 0; w < BLK / 64; ++w) s += r[w];
        out[0] = s;
    }
}

extern "C" void kernel_launch(void* const* d_in, const int* in_sizes, int n_in,
                              void* d_out, int out_size, void* d_ws, size_t ws_size,
                              hipStream_t stream)
{
    const float* a0 = (const float*)d_in[0];
    const float* a2 = (const float*)d_in[1];
    float* out      = (float*)d_out;
    float* partials = (float*)d_ws;              // nblk floats, fully overwritten
    const int B = in_sizes[0] / T_LEN;           // 4096

    const int nblk = B / RPB;                    // 1024
    actloss_partial<<<nblk, BLK, 0, stream>>>(a0, a2, partials);
    actloss_final<<<1, BLK, 0, stream>>>(partials, nblk / 4, out);
}

// Round 5
// 75.571 us; speedup vs baseline: 2.0092x; 1.0131x over previous
//
#include <hip/hip_runtime.h>
#include <math.h>

// ActELoss, symmetric reformulation, two-kernel (the structure that wins).
// S = sum_{b,i,j=0..10} exp(-|a0[i]-p0[i+j]|/2)*|a2[i]-p2[i+j]|, p = pad(6 first,5 last)
// Symmetry f(i,m)=f(m,i), f(i,i)=0:
//   S = 2*sum_{k=1..4} sum_i f(i,i+k) + sum_{k=5,6} sum_i f(i,i+k)
//     + sum_{i=1..5}(6-i) f(i,0) + sum_{i=746..748}(i-745) f(i,749)
// plus 0.1 * sum_b ||a0-a2||_2.
//
// SESSION LESSONS (do not re-learn):
//  R1: cooperative launch / grid.sync wedges the container under graph capture.
//  R2: single-address atomicAdd ticket: 4096 x ~17ns serialized = ~70us tail.
//  R3: spread tickets fixed atomics, but __threadfence() (device release) costs
//      ~15us across 1024 blocks on gfx950's 8 non-coherent L2s. ANY in-kernel
//      device-scope release loses to the dispatch boundary's free HW flush.
//  R4: 1024 blocks x 4 rows = +3us vs 4096 x 1 (longer per-block serial chain,
//      less ramp parallelism). Granularity matters; float4 staging is good.
// => This round: 2048 blocks x 2 rows. float4 staging kept (2 rows = 375
//    float4, base b*6000B is 16B-aligned), per-block serial chain halved,
//    8 blocks/CU at 12KB LDS. Partials pre-summed per block (final reads 8KB).
//    Decision rule: if within +-2us of R4, controllable slack is exhausted
//    (fill 42.5us harness-fixed at its own BW ceiling + ~20us graph overhead
//    + kernels at latency floor) -> declare ROOFLINE.

#define T_LEN 750
#define BLK   256
#define CPT   3            // positions per thread; 250 active threads per row
#define NACT  (T_LEN / CPT)
#define RPB   2            // rows per block
#define L2E_HALF 0.72134752044f   // 0.5 * log2(e)

__global__ __launch_bounds__(BLK) void actloss_partial(
    const float* __restrict__ a0, const float* __restrict__ a2,
    float* __restrict__ partials)
{
    // Flat 2-row staging: row r at s[r*750]; 8 pad floats at [1500..1507].
    // Out-of-row reads (i0+k >= 750) hit the next row's head / pad: any finite
    // value is fine because ad2 is masked to 0 for those terms.
    __shared__ float4 s0v[377];
    __shared__ float4 s2v[377];
    float* s0 = (float*)s0v;
    float* s2 = (float*)s2v;
    __shared__ float rl[RPB][BLK / 64], rs[RPB][BLK / 64];

    const int b   = blockIdx.x;
    const int tid = threadIdx.x;
    const int b0  = b * RPB;

    // 2 contiguous rows = 1500 floats = 375 float4 (base byte off b*6000 % 16 == 0)
    const float* __restrict__ g0 = a0 + (size_t)b0 * T_LEN;
    const float* __restrict__ g2 = a2 + (size_t)b0 * T_LEN;
    {
        const float4* __restrict__ v0 = (const float4*)g0;
        const float4* __restrict__ v2 = (const float4*)g2;
        for (int k = tid; k < 375; k += BLK) {
            s0v[k] = v0[k];
            s2v[k] = v2[k];
        }
        if (tid < 8) {            // pad: replicate last element (masked anyway)
            s0[1500 + tid] = g0[RPB * T_LEN - 1];
            s2[1500 + tid] = g2[RPB * T_LEN - 1];
        }
    }
    __syncthreads();

    float lossA[RPB], sqA[RPB];
#pragma unroll
    for (int r = 0; r < RPB; ++r) { lossA[r] = 0.0f; sqA[r] = 0.0f; }

    if (tid < NACT) {
        const int i0 = tid * CPT;
#pragma unroll
        for (int r = 0; r < RPB; ++r) {
            const float* __restrict__ s0r = s0 + r * T_LEN;
            const float* __restrict__ s2r = s2 + r * T_LEN;
            float r0[CPT + 6], r2[CPT + 6];
#pragma unroll
            for (int k = 0; k < CPT + 6; ++k) {
                r0[k] = s0r[i0 + k];
                r2[k] = s2r[i0 + k];
            }
            float loss1 = 0.0f, loss2 = 0.0f, sq = 0.0f;
#pragma unroll
            for (int ci = 0; ci < CPT; ++ci) {
                const float c0 = r0[ci];
                const float c2 = r2[ci];
#pragma unroll
                for (int k = 1; k <= 6; ++k) {
                    const float wv  = __builtin_amdgcn_exp2f(
                                          -L2E_HALF * fabsf(c0 - r0[ci + k]));
                    float ad2 = fabsf(c2 - r2[ci + k]);
                    ad2 = (i0 + ci + k < T_LEN) ? ad2 : 0.0f;  // mask out-of-range
                    if (k <= 4) loss2 = fmaf(wv, ad2, loss2);
                    else        loss1 = fmaf(wv, ad2, loss1);
                }
                const float d = c0 - c2;
                sq = fmaf(d, d, sq);
            }
            lossA[r] = fmaf(2.0f, loss2, loss1);
            sqA[r]   = sq;
        }
    } else if (tid == NACT) {
        // clamp edge extras (8 terms per row)
#pragma unroll
        for (int r = 0; r < RPB; ++r) {
            const float* __restrict__ s0r = s0 + r * T_LEN;
            const float* __restrict__ s2r = s2 + r * T_LEN;
            float loss1 = 0.0f;
#pragma unroll
            for (int i = 1; i <= 5; ++i) {
                const float wv = __builtin_amdgcn_exp2f(-L2E_HALF * fabsf(s0r[i] - s0r[0]));
                loss1 = fmaf(wv * (float)(6 - i), fabsf(s2r[i] - s2r[0]), loss1);
            }
#pragma unroll
            for (int i = 746; i <= 748; ++i) {
                const float wv = __builtin_amdgcn_exp2f(-L2E_HALF * fabsf(s0r[i] - s0r[T_LEN - 1]));
                loss1 = fmaf(wv * (float)(i - 745), fabsf(s2r[i] - s2r[T_LEN - 1]), loss1);
            }
            lossA[r] = loss1;
        }
    }

    // wave64 shuffle reduce, both rows in one pass (tree identical to R0 per row)
#pragma unroll
    for (int off = 32; off > 0; off >>= 1) {
#pragma unroll
        for (int r = 0; r < RPB; ++r) {
            lossA[r] += __shfl_down(lossA[r], off, 64);
            sqA[r]   += __shfl_down(sqA[r],   off, 64);
        }
    }
    const int wid  = tid >> 6;
    const int lane = tid & 63;
    if (lane == 0) {
#pragma unroll
        for (int r = 0; r < RPB; ++r) { rl[r][wid] = lossA[r]; rs[r][wid] = sqA[r]; }
    }
    __syncthreads();

    if (tid == 0) {
        float p[RPB];
#pragma unroll
        for (int r = 0; r < RPB; ++r) {
            float L = 0.0f, S = 0.0f;
#pragma unroll
            for (int w = 0; w < BLK / 64; ++w) { L += rl[r][w]; S += rs[r][w]; }
            p[r] = L + 0.1f * sqrtf(S);          // same per-row value as R0
        }
        partials[b] = p[0] + p[1];               // pre-sum: final reads 8KB
    }
}

__global__ __launch_bounds__(BLK) void actloss_final(
    const float* __restrict__ partials, int n4, float* __restrict__ out)
{
    // n4 = number of float4s (2048 partials / 4 = 512): two per thread.
    const float4* __restrict__ p4 = (const float4*)partials;
    float v = 0.0f;
    for (int k = threadIdx.x; k < n4; k += BLK) {
        const float4 x = p4[k];
        v += (x.x + x.y) + (x.z + x.w);
    }
#pragma unroll
    for (int off = 32; off > 0; off >>= 1) v += __shfl_down(v, off, 64);
    __shared__ float r[BLK / 64];
    if ((threadIdx.x & 63) == 0) r[threadIdx.x >> 6] = v;
    __syncthreads();
    if (threadIdx.x == 0) {
        float s = 0.0f;
#pragma unroll
        for (int w = 0; w < BLK / 64; ++w) s += r[w];
        out[0] = s;
    }
}

extern "C" void kernel_launch(void* const* d_in, const int* in_sizes, int n_in,
                              void* d_out, int out_size, void* d_ws, size_t ws_size,
                              hipStream_t stream)
{
    const float* a0 = (const float*)d_in[0];
    const float* a2 = (const float*)d_in[1];
    float* out      = (float*)d_out;
    float* partials = (float*)d_ws;              // nblk floats, fully overwritten
    const int B = in_sizes[0] / T_LEN;           // 4096

    const int nblk = B / RPB;                    // 2048
    actloss_partial<<<nblk, BLK, 0, stream>>>(a0, a2, partials);
    actloss_final<<<1, BLK, 0, stream>>>(partials, nblk / 4, out);
}